// Round 5
// baseline (162.364 us; speedup 1.0000x reference)
//
#include <hip/hip_runtime.h>

#define SEQ 512
#define BZ  64
#define DIN 1024
#define HID 256
#define DOUT 1024
#define NLANG 16

typedef __attribute__((ext_vector_type(8))) __bf16 bf16x8;
typedef __attribute__((ext_vector_type(4))) float f32x4;

#define LGKM0 asm volatile("s_waitcnt lgkmcnt(0)" ::: "memory")

__device__ __forceinline__ unsigned short f2bf(float f) {
    return __builtin_bit_cast(unsigned short, (__bf16)f);
}
__device__ __forceinline__ unsigned int f2bf_pack(float lo, float hi) {
    return (unsigned int)f2bf(lo) | ((unsigned int)f2bf(hi) << 16);
}

// W[lid][K][N] f32  ->  Wf[lid][N/16][K/32][64 lanes][8] bf16 (fragment-major).
// Fragment (n16,k32), lane l, elem j  =  W[lid][k32*32+(l>>4)*8+j][n16*16+(l&15)].
template<int K, int N>
__global__ __launch_bounds__(256)
void prep_frags(const float* __restrict__ src, unsigned short* __restrict__ dst) {
    constexpr int K32 = K / 32, N16 = N / 16;
    const int gid = blockIdx.x * 256 + threadIdx.x;
    const int l   = gid & 63;
    const int f   = gid >> 6;
    const int k32 = f & (K32 - 1);
    const int n16 = (f / K32) & (N16 - 1);
    const int lid = f / (K32 * N16);
    const float* s = src + ((long)lid * K + k32 * 32 + (l >> 4) * 8) * N + n16 * 16 + (l & 15);
    unsigned short o[8];
#pragma unroll
    for (int j = 0; j < 8; ++j) o[j] = f2bf(s[(long)j * N]);
    uint4 v;
    v.x = (unsigned int)o[0] | ((unsigned int)o[1] << 16);
    v.y = (unsigned int)o[2] | ((unsigned int)o[3] << 16);
    v.z = (unsigned int)o[4] | ((unsigned int)o[5] << 16);
    v.w = (unsigned int)o[6] | ((unsigned int)o[7] << 16);
    *(uint4*)(dst + (long)gid * 8) = v;
}

// Fused per-language MLP. One block per (b, st): 64 seq rows, 4 waves.
// Raw s_barrier (+ manual lgkmcnt(0)) so register-destined weight prefetch
// survives barriers; ring-3 prefetch on all global fragment streams.
__global__ __launch_bounds__(256, 3)
void fused_mlp(const float* __restrict__ x,
               const unsigned short* __restrict__ W1f,
               const float* __restrict__ b1,
               const unsigned short* __restrict__ W2f,
               const float* __restrict__ b2,
               const int* __restrict__ lang,
               float* __restrict__ y) {
    __shared__ unsigned short sA[2][64 * 64];   // 2 x 8 KiB x-tile (bf16, swizzled)
    __shared__ unsigned short sH[64 * 256];     // 32 KiB h-tile (bf16, swizzled)

    // XCD affinity: all 8 st-tiles of one b (same lid -> same W) on one XCD.
    const int n  = blockIdx.x;
    const int v  = ((n & 7) << 6) | (n >> 3);
    const int b  = v >> 3;
    const int st = v & 7;

    const int t  = threadIdx.x;
    const int l  = t & 63;
    const int w  = t >> 6;
    const int lid = lang[b];
    const int s0  = st * 64;
    const long xbase = (long)s0 * BZ * DIN + (long)b * DIN;

    const f32x4 z4 = {0.f, 0.f, 0.f, 0.f};

    // ---------------- phase 1 ----------------
    f32x4 acc1[4][4];
#pragma unroll
    for (int mi = 0; mi < 4; ++mi)
#pragma unroll
        for (int ni = 0; ni < 4; ++ni) acc1[mi][ni] = z4;

    float4 xr[4];
#define LOADX(KT)                                                                 \
    {                                                                             \
        _Pragma("unroll")                                                         \
        for (int j = 0; j < 4; ++j) {                                             \
            int u = t + 256 * j, m = u >> 4, c4 = u & 15;                         \
            xr[j] = *(const float4*)(x + xbase + (long)m * (BZ * DIN) + (KT) * 64 + c4 * 4); \
        }                                                                         \
    }
#define WRITEX(BUF)                                                               \
    {                                                                             \
        char* cA = (char*)sA[BUF];                                                \
        _Pragma("unroll")                                                         \
        for (int j = 0; j < 4; ++j) {                                             \
            int u = t + 256 * j, m = u >> 4, c4 = u & 15;                         \
            uint2 p;                                                              \
            p.x = f2bf_pack(xr[j].x, xr[j].y);                                    \
            p.y = f2bf_pack(xr[j].z, xr[j].w);                                    \
            *(uint2*)(cA + (((m * 128) + c4 * 8) ^ ((m & 7) << 4))) = p;          \
        }                                                                         \
    }

    const unsigned short* w1p = W1f + (((long)lid * 16 + w * 4) * 32) * 512 + (long)l * 8;
    // frag (ni, k32) at w1p + ni*16384 + k32*512   (shorts)

    float bvv[4];
#pragma unroll
    for (int ni = 0; ni < 4; ++ni)
        bvv[ni] = b1[lid * HID + w * 64 + ni * 16 + (l & 15)];

    LOADX(0);
    bf16x8 ring1[3][4];
#pragma unroll
    for (int s = 0; s < 2; ++s)
#pragma unroll
        for (int ni = 0; ni < 4; ++ni)
            ring1[s][ni] = __builtin_bit_cast(bf16x8,
                *(const uint4*)(w1p + (long)ni * 16384 + s * 512));
    WRITEX(0);
    LGKM0;
    __builtin_amdgcn_s_barrier();

#pragma unroll
    for (int kt = 0; kt < 16; ++kt) {
        if (kt < 15) LOADX(kt + 1);
        char* cA = (char*)sA[kt & 1];
#pragma unroll
        for (int ks = 0; ks < 2; ++ks) {
            const int k32 = kt * 2 + ks;
            if (k32 < 30) {
#pragma unroll
                for (int ni = 0; ni < 4; ++ni)
                    ring1[(k32 + 2) % 3][ni] = __builtin_bit_cast(bf16x8,
                        *(const uint4*)(w1p + (long)ni * 16384 + (k32 + 2) * 512));
            }
            bf16x8 av[4];
#pragma unroll
            for (int mi = 0; mi < 4; ++mi) {
                int row = mi * 16 + (l & 15);
                int ch  = ks * 4 + (l >> 4);
                av[mi] = __builtin_bit_cast(bf16x8,
                    *(const uint4*)(cA + row * 128 + ((ch ^ (row & 7)) << 4)));
            }
#pragma unroll
            for (int mi = 0; mi < 4; ++mi)
#pragma unroll
                for (int ni = 0; ni < 4; ++ni)
                    acc1[mi][ni] = __builtin_amdgcn_mfma_f32_16x16x32_bf16(
                        av[mi], ring1[k32 % 3][ni], acc1[mi][ni], 0, 0, 0);
        }
        if (kt < 15) {
            WRITEX((kt & 1) ^ 1);
            LGKM0;
            __builtin_amdgcn_s_barrier();
        }
    }

    // epilogue 1: bias + relu + bf16 -> swizzled sH
    {
        char* cH = (char*)sH;
#pragma unroll
        for (int mi = 0; mi < 4; ++mi)
#pragma unroll
            for (int r = 0; r < 4; ++r) {
                int row = mi * 16 + (l >> 4) * 4 + r;
#pragma unroll
                for (int ni = 0; ni < 4; ++ni) {
                    int col = w * 64 + ni * 16 + (l & 15);
                    float vv = acc1[mi][ni][r] + bvv[ni];
                    vv = vv > 0.f ? vv : 0.f;
                    *(unsigned short*)(cH + row * 512 + (((col >> 3) ^ (row & 7)) << 4)
                                       + (col & 7) * 2) = f2bf(vv);
                }
            }
    }
    LGKM0;
    __builtin_amdgcn_s_barrier();

    // ---------------- phase 2 ----------------
    char* cH = (char*)sH;
    const unsigned short* w2p = W2f + (((long)lid * 64 + w * 16) * 8) * 512 + (long)l * 8;
    // frag (nc,ni,ks) at w2p + (nc*4+ni)*4096 + ks*512   (shorts)

    bf16x8 pv[3][4], av2[2][4];
#pragma unroll
    for (int s = 0; s < 2; ++s)
#pragma unroll
        for (int ni = 0; ni < 4; ++ni)
            pv[s][ni] = __builtin_bit_cast(bf16x8,
                *(const uint4*)(w2p + (long)ni * 4096 + s * 512));
#pragma unroll
    for (int mi = 0; mi < 4; ++mi) {
        int row = mi * 16 + (l & 15);
        int ch  = (l >> 4);   // ks = 0
        av2[0][mi] = __builtin_bit_cast(bf16x8,
            *(const uint4*)(cH + row * 512 + ((ch ^ (row & 7)) << 4)));
    }

    f32x4 acc[4][4];
    float b2v[4];
#pragma unroll
    for (int step = 0; step < 32; ++step) {
        const int nc = step >> 3, ks = step & 7;
        if (ks == 0) {
#pragma unroll
            for (int mi = 0; mi < 4; ++mi)
#pragma unroll
                for (int ni = 0; ni < 4; ++ni) acc[mi][ni] = z4;
#pragma unroll
            for (int ni = 0; ni < 4; ++ni)
                b2v[ni] = b2[lid * DOUT + w * 256 + nc * 64 + ni * 16 + (l & 15)];
        }
        if (step < 30) {
            const int s2 = step + 2, nc2 = s2 >> 3, ks2 = s2 & 7;
#pragma unroll
            for (int ni = 0; ni < 4; ++ni)
                pv[s2 % 3][ni] = __builtin_bit_cast(bf16x8,
                    *(const uint4*)(w2p + (long)(nc2 * 4 + ni) * 4096 + ks2 * 512));
        }
        if (step < 31) {
            const int s1 = step + 1, ks1 = s1 & 7;
#pragma unroll
            for (int mi = 0; mi < 4; ++mi) {
                int row = mi * 16 + (l & 15);
                int ch  = ks1 * 4 + (l >> 4);
                av2[s1 & 1][mi] = __builtin_bit_cast(bf16x8,
                    *(const uint4*)(cH + row * 512 + ((ch ^ (row & 7)) << 4)));
            }
        }
#pragma unroll
        for (int mi = 0; mi < 4; ++mi)
#pragma unroll
            for (int ni = 0; ni < 4; ++ni)
                acc[mi][ni] = __builtin_amdgcn_mfma_f32_16x16x32_bf16(
                    av2[step & 1][mi], pv[step % 3][ni], acc[mi][ni], 0, 0, 0);
        if (ks == 7) {
#pragma unroll
            for (int mi = 0; mi < 4; ++mi)
#pragma unroll
                for (int r = 0; r < 4; ++r) {
                    int row = mi * 16 + (l >> 4) * 4 + r;
#pragma unroll
                    for (int ni = 0; ni < 4; ++ni) {
                        int col = w * 256 + nc * 64 + ni * 16 + (l & 15);
                        y[((long)(s0 + row) * BZ + b) * DOUT + col] =
                            acc[mi][ni][r] + b2v[ni];
                    }
                }
        }
    }
#undef LOADX
#undef WRITEX
}

extern "C" void kernel_launch(void* const* d_in, const int* in_sizes, int n_in,
                              void* d_out, int out_size, void* d_ws, size_t ws_size,
                              hipStream_t stream) {
    const float* x    = (const float*)d_in[0];
    const int*   lang = (const int*)d_in[1];
    const float* W1   = (const float*)d_in[2];
    const float* b1   = (const float*)d_in[3];
    const float* W2   = (const float*)d_in[4];
    const float* b2   = (const float*)d_in[5];
    float* y = (float*)d_out;

    // ws: W1f bf16 [16][16][32][64][8] (8 MiB) | W2f bf16 [16][64][8][64][8] (8 MiB)
    unsigned short* W1f = (unsigned short*)d_ws;
    unsigned short* W2f = (unsigned short*)((char*)d_ws + (size_t)NLANG * HID * DIN * 2);

    prep_frags<DIN, HID><<<2048, 256, 0, stream>>>(W1, W1f);
    prep_frags<HID, DOUT><<<2048, 256, 0, stream>>>(W2, W2f);

    fused_mlp<<<dim3(BZ * (SEQ / 64)), 256, 0, stream>>>(x, W1f, b1, W2f, b2, lang, y);
}

// Round 6
// 150.463 us; speedup vs baseline: 1.0791x; 1.0791x over previous
//
#include <hip/hip_runtime.h>

#define SEQ 512
#define BZ  64
#define DIN 1024
#define HID 256
#define DOUT 1024
#define NLANG 16

typedef __attribute__((ext_vector_type(8))) __bf16 bf16x8;
typedef __attribute__((ext_vector_type(4))) float f32x4;

__device__ __forceinline__ unsigned short f2bf(float f) {
    return __builtin_bit_cast(unsigned short, (__bf16)f);
}
__device__ __forceinline__ unsigned int f2bf_pack(float lo, float hi) {
    return (unsigned int)f2bf(lo) | ((unsigned int)f2bf(hi) << 16);
}

// W[lid][K][N] f32  ->  Wf[lid][N/16][K/32][64 lanes][8] bf16 (fragment-major).
// Fragment (n16,k32), lane l, elem j  =  W[lid][k32*32+(l>>4)*8+j][n16*16+(l&15)].
template<int K, int N>
__global__ __launch_bounds__(256)
void prep_frags(const float* __restrict__ src, unsigned short* __restrict__ dst) {
    constexpr int K32 = K / 32, N16 = N / 16;
    const int gid = blockIdx.x * 256 + threadIdx.x;
    const int l   = gid & 63;
    const int f   = gid >> 6;
    const int k32 = f & (K32 - 1);
    const int n16 = (f / K32) & (N16 - 1);
    const int lid = f / (K32 * N16);
    const float* s = src + ((long)lid * K + k32 * 32 + (l >> 4) * 8) * N + n16 * 16 + (l & 15);
    unsigned short o[8];
#pragma unroll
    for (int j = 0; j < 8; ++j) o[j] = f2bf(s[(long)j * N]);
    uint4 v;
    v.x = (unsigned int)o[0] | ((unsigned int)o[1] << 16);
    v.y = (unsigned int)o[2] | ((unsigned int)o[3] << 16);
    v.z = (unsigned int)o[4] | ((unsigned int)o[5] << 16);
    v.w = (unsigned int)o[6] | ((unsigned int)o[7] << 16);
    *(uint4*)(dst + (long)gid * 8) = v;
}

// Fused per-language MLP. One block per (b, st): 64 seq rows, 8 waves (512 thr).
// Phase 1: BK=256 (4 K-steps, each x row read as one contiguous 1KB wave load),
//          single-buffered 32KB sX, h -> 32KB swizzled sH.
// Phase 2: per wave 64 rows x 128 cols, A-frags from sH + W2-frags from L2,
//          depth-1 ping-pong, no barriers.
__global__ __launch_bounds__(512, 4)
void fused_mlp(const float* __restrict__ x,
               const unsigned short* __restrict__ W1f,
               const float* __restrict__ b1,
               const unsigned short* __restrict__ W2f,
               const float* __restrict__ b2,
               const int* __restrict__ lang,
               float* __restrict__ y) {
    __shared__ unsigned short sX[64 * 256];   // 32 KiB x-tile bf16, swizzled
    __shared__ unsigned short sH[64 * 256];   // 32 KiB h-tile bf16, swizzled
    char* cX = (char*)sX;
    char* cH = (char*)sH;

    const int b  = blockIdx.x;
    const int st = blockIdx.y;
    const int t  = threadIdx.x;
    const int l  = t & 63;
    const int w  = t >> 6;                    // 0..7
    const int lid = lang[b];
    const int s0  = st * 64;
    const long xstride = (long)BZ * DIN;
    const float* xb = x + (long)s0 * xstride + (long)b * DIN;

    const f32x4 z4 = {0.f, 0.f, 0.f, 0.f};

    // ---------------- phase 1 ----------------
    f32x4 acc1[4][2];
#pragma unroll
    for (int mi = 0; mi < 4; ++mi)
#pragma unroll
        for (int ni = 0; ni < 2; ++ni) acc1[mi][ni] = z4;

    float4 xr[8];
    // wave w, sub-step j: row 8*j+w, lane l covers f32 cols l*4..l*4+3 (1KB/wave contiguous)
#define LOADX(KT)                                                                  \
    {                                                                              \
        _Pragma("unroll")                                                          \
        for (int j = 0; j < 8; ++j)                                                \
            xr[j] = *(const float4*)(xb + (long)(8 * j + w) * xstride + (KT) * 256 + l * 4); \
    }
#define WRITEX                                                                     \
    {                                                                              \
        _Pragma("unroll")                                                          \
        for (int j = 0; j < 8; ++j) {                                              \
            int row = 8 * j + w;                                                   \
            int ch = l >> 1, half = l & 1;                                         \
            uint2 p;                                                               \
            p.x = f2bf_pack(xr[j].x, xr[j].y);                                     \
            p.y = f2bf_pack(xr[j].z, xr[j].w);                                     \
            *(uint2*)(cX + row * 512 + ((ch ^ (row & 7)) << 4) + half * 8) = p;    \
        }                                                                          \
    }

    const unsigned short* w1p = W1f + (((long)lid * 16 + w * 2) * 32) * 512 + (long)l * 8;
    // frag (ni, k32) at w1p + ni*16384 + k32*512  (shorts)

    float bvv[2];
#pragma unroll
    for (int ni = 0; ni < 2; ++ni)
        bvv[ni] = b1[lid * HID + w * 32 + ni * 16 + (l & 15)];

    LOADX(0);
    bf16x8 bvp[2][2];
#pragma unroll
    for (int ni = 0; ni < 2; ++ni)
        bvp[0][ni] = __builtin_bit_cast(bf16x8, *(const uint4*)(w1p + (long)ni * 16384));

#pragma unroll 1
    for (int kt = 0; kt < 4; ++kt) {
        WRITEX;
        __syncthreads();
        if (kt < 3) LOADX(kt + 1);
#pragma unroll
        for (int j = 0; j < 8; ++j) {
            const int k32 = kt * 8 + j;
            if (kt < 3 || j < 7) {
#pragma unroll
                for (int ni = 0; ni < 2; ++ni)
                    bvp[(j + 1) & 1][ni] = __builtin_bit_cast(bf16x8,
                        *(const uint4*)(w1p + (long)ni * 16384 + (k32 + 1) * 512));
            }
            bf16x8 av[4];
#pragma unroll
            for (int mi = 0; mi < 4; ++mi) {
                int row = mi * 16 + (l & 15);
                int ch  = j * 4 + (l >> 4);
                av[mi] = __builtin_bit_cast(bf16x8,
                    *(const uint4*)(cX + row * 512 + ((ch ^ (row & 7)) << 4)));
            }
#pragma unroll
            for (int mi = 0; mi < 4; ++mi)
#pragma unroll
                for (int ni = 0; ni < 2; ++ni)
                    acc1[mi][ni] = __builtin_amdgcn_mfma_f32_16x16x32_bf16(
                        av[mi], bvp[j & 1][ni], acc1[mi][ni], 0, 0, 0);
        }
        __syncthreads();
    }

    // epilogue 1: bias + relu + bf16 -> swizzled sH
#pragma unroll
    for (int mi = 0; mi < 4; ++mi)
#pragma unroll
        for (int r = 0; r < 4; ++r) {
            int row = mi * 16 + (l >> 4) * 4 + r;
#pragma unroll
            for (int ni = 0; ni < 2; ++ni) {
                int col = w * 32 + ni * 16 + (l & 15);
                float v = acc1[mi][ni][r] + bvv[ni];
                v = v > 0.f ? v : 0.f;
                *(unsigned short*)(cH + row * 512 + (((col >> 3) ^ (row & 7)) << 4)
                                   + (col & 7) * 2) = f2bf(v);
            }
        }
    __syncthreads();

    // ---------------- phase 2 ----------------
    const unsigned short* w2p = W2f + (((long)lid * 64 + w * 8) * 8) * 512 + (long)l * 8;
    // frag (nq = nc*4+ni, ks) at w2p + nq*4096 + ks*512  (shorts)

    bf16x8 pv[2][4], av2[2][4];
#pragma unroll
    for (int ni = 0; ni < 4; ++ni)
        pv[0][ni] = __builtin_bit_cast(bf16x8, *(const uint4*)(w2p + (long)ni * 4096));
#pragma unroll
    for (int mi = 0; mi < 4; ++mi) {
        int row = mi * 16 + (l & 15);
        int ch  = (l >> 4);   // ks = 0
        av2[0][mi] = __builtin_bit_cast(bf16x8,
            *(const uint4*)(cH + row * 512 + ((ch ^ (row & 7)) << 4)));
    }

    f32x4 acc[4][4];
    float b2v[4];
#pragma unroll
    for (int s = 0; s < 16; ++s) {
        const int nc = s >> 3, ks = s & 7, cur = s & 1;
        if (ks == 0) {
#pragma unroll
            for (int mi = 0; mi < 4; ++mi)
#pragma unroll
                for (int ni = 0; ni < 4; ++ni) acc[mi][ni] = z4;
#pragma unroll
            for (int ni = 0; ni < 4; ++ni)
                b2v[ni] = b2[lid * DOUT + w * 128 + nc * 64 + ni * 16 + (l & 15)];
        }
        if (s < 15) {
            const int ns = s + 1, nq = (ns >> 3) * 4, ks1 = ns & 7;
#pragma unroll
            for (int ni = 0; ni < 4; ++ni)
                pv[cur ^ 1][ni] = __builtin_bit_cast(bf16x8,
                    *(const uint4*)(w2p + (long)(nq + ni) * 4096 + ks1 * 512));
#pragma unroll
            for (int mi = 0; mi < 4; ++mi) {
                int row = mi * 16 + (l & 15);
                int ch  = ks1 * 4 + (l >> 4);
                av2[cur ^ 1][mi] = __builtin_bit_cast(bf16x8,
                    *(const uint4*)(cH + row * 512 + ((ch ^ (row & 7)) << 4)));
            }
        }
#pragma unroll
        for (int mi = 0; mi < 4; ++mi)
#pragma unroll
            for (int ni = 0; ni < 4; ++ni)
                acc[mi][ni] = __builtin_amdgcn_mfma_f32_16x16x32_bf16(
                    av2[cur][mi], pv[cur][ni], acc[mi][ni], 0, 0, 0);
        if (ks == 7) {
#pragma unroll
            for (int mi = 0; mi < 4; ++mi)
#pragma unroll
                for (int r = 0; r < 4; ++r) {
                    int row = mi * 16 + (l >> 4) * 4 + r;
#pragma unroll
                    for (int ni = 0; ni < 4; ++ni) {
                        int col = w * 128 + nc * 64 + ni * 16 + (l & 15);
                        y[((long)(s0 + row) * BZ + b) * DOUT + col] =
                            acc[mi][ni][r] + b2v[ni];
                    }
                }
        }
    }
#undef LOADX
#undef WRITEX
}

extern "C" void kernel_launch(void* const* d_in, const int* in_sizes, int n_in,
                              void* d_out, int out_size, void* d_ws, size_t ws_size,
                              hipStream_t stream) {
    const float* x    = (const float*)d_in[0];
    const int*   lang = (const int*)d_in[1];
    const float* W1   = (const float*)d_in[2];
    const float* b1   = (const float*)d_in[3];
    const float* W2   = (const float*)d_in[4];
    const float* b2   = (const float*)d_in[5];
    float* y = (float*)d_out;

    // ws: W1f bf16 [16][16][32][64][8] (8 MiB) | W2f bf16 [16][64][8][64][8] (8 MiB)
    unsigned short* W1f = (unsigned short*)d_ws;
    unsigned short* W2f = (unsigned short*)((char*)d_ws + (size_t)NLANG * HID * DIN * 2);

    prep_frags<DIN, HID><<<2048, 256, 0, stream>>>(W1, W1f);
    prep_frags<HID, DOUT><<<2048, 256, 0, stream>>>(W2, W2f);

    fused_mlp<<<dim3(BZ, SEQ / 64), 512, 0, stream>>>(x, W1f, b1, W2f, b2, lang, y);
}

// Round 7
// 95.977 us; speedup vs baseline: 1.6917x; 1.5677x over previous
//
#include <hip/hip_runtime.h>

#define SEQ 512
#define BZ  64
#define DIN 1024
#define HID 256
#define DOUT 1024
#define NLANG 16

typedef __attribute__((ext_vector_type(8))) __bf16 bf16x8;
typedef __attribute__((ext_vector_type(4))) float f32x4;

__device__ __forceinline__ unsigned short f2bf(float f) {
    return __builtin_bit_cast(unsigned short, (__bf16)f);
}
__device__ __forceinline__ unsigned int f2bf_pack(float lo, float hi) {
    return (unsigned int)f2bf(lo) | ((unsigned int)f2bf(hi) << 16);
}

// W[lid][K][N] f32  ->  Wf[lid][N/16][K/32][64 lanes][8] bf16 (fragment-major).
// Fragment (n16,k32), lane l, elem j  =  W[lid][k32*32+(l>>4)*8+j][n16*16+(l&15)].
template<int K, int N>
__global__ __launch_bounds__(256)
void prep_frags(const float* __restrict__ src, unsigned short* __restrict__ dst) {
    constexpr int K32 = K / 32, N16 = N / 16;
    const int gid = blockIdx.x * 256 + threadIdx.x;
    const int l   = gid & 63;
    const int f   = gid >> 6;
    const int k32 = f & (K32 - 1);
    const int n16 = (f / K32) & (N16 - 1);
    const int lid = f / (K32 * N16);
    const float* s = src + ((long)lid * K + k32 * 32 + (l >> 4) * 8) * N + n16 * 16 + (l & 15);
    unsigned short o[8];
#pragma unroll
    for (int j = 0; j < 8; ++j) o[j] = f2bf(s[(long)j * N]);
    uint4 v;
    v.x = (unsigned int)o[0] | ((unsigned int)o[1] << 16);
    v.y = (unsigned int)o[2] | ((unsigned int)o[3] << 16);
    v.z = (unsigned int)o[4] | ((unsigned int)o[5] << 16);
    v.w = (unsigned int)o[6] | ((unsigned int)o[7] << 16);
    *(uint4*)(dst + (long)gid * 8) = v;
}

// Fused per-language MLP. One block per (b, st): 64 seq rows, 8 waves (512 thr).
// Structure identical to the 102us R3 kernel; only the wave count doubled
// (16 waves/CU instead of 8) with per-wave output slices halved.
// Phase 1: h64x256 = relu(x @ W1 + b1); BK=64 double-buffered sA; per wave 32 cols.
// Phase 2: y64x1024 = h @ W2 + b2; per wave 128 cols; A-frags from swizzled sH,
// W2-frags from L2 with depth-1 ping-pong; no barriers.
__global__ __launch_bounds__(512, 2)
void fused_mlp(const float* __restrict__ x,
               const unsigned short* __restrict__ W1f,
               const float* __restrict__ b1,
               const unsigned short* __restrict__ W2f,
               const float* __restrict__ b2,
               const int* __restrict__ lang,
               float* __restrict__ y) {
    __shared__ unsigned short sA[2][64 * 64];   // 2 x 8 KiB x-tile (bf16, swizzled)
    __shared__ unsigned short sH[64 * 256];     // 32 KiB h-tile (bf16, swizzled)
    char* cH = (char*)sH;

    const int b  = blockIdx.x;
    const int st = blockIdx.y;
    const int t  = threadIdx.x;
    const int l  = t & 63;
    const int w  = t >> 6;                      // 0..7
    const int lid = lang[b];
    const int s0  = st * 64;
    const long xstride = (long)BZ * DIN;
    const float* xb = x + (long)s0 * xstride + (long)b * DIN;

    const f32x4 z4 = {0.f, 0.f, 0.f, 0.f};

    // ---------------- phase 1 ----------------
    f32x4 acc1[4][2];
#pragma unroll
    for (int mi = 0; mi < 4; ++mi)
#pragma unroll
        for (int ni = 0; ni < 2; ++ni) acc1[mi][ni] = z4;

    float4 xr[2];
#define LOADX(KT)                                                                  \
    {                                                                              \
        _Pragma("unroll")                                                          \
        for (int j = 0; j < 2; ++j) {                                              \
            int u = t + 512 * j, m = u >> 4, c4 = u & 15;                          \
            xr[j] = *(const float4*)(xb + (long)m * xstride + (KT) * 64 + c4 * 4); \
        }                                                                          \
    }
#define WRITEX(BUF)                                                               \
    {                                                                             \
        char* cA = (char*)sA[BUF];                                                \
        _Pragma("unroll")                                                         \
        for (int j = 0; j < 2; ++j) {                                             \
            int u = t + 512 * j, m = u >> 4, c4 = u & 15;                         \
            uint2 p;                                                              \
            p.x = f2bf_pack(xr[j].x, xr[j].y);                                    \
            p.y = f2bf_pack(xr[j].z, xr[j].w);                                    \
            *(uint2*)(cA + (((m * 128) + c4 * 8) ^ ((m & 7) << 4))) = p;          \
        }                                                                         \
    }

    const unsigned short* w1p = W1f + (((long)lid * 16 + w * 2) * 32) * 512 + (long)l * 8;
    // frag (ni, k32) at w1p + ni*16384 + k32*512   (shorts)

    float bvv[2];
#pragma unroll
    for (int ni = 0; ni < 2; ++ni)
        bvv[ni] = b1[lid * HID + w * 32 + ni * 16 + (l & 15)];

    LOADX(0);
    WRITEX(0);
    bf16x8 bvp[2][2];
#pragma unroll
    for (int ni = 0; ni < 2; ++ni)
        bvp[0][ni] = __builtin_bit_cast(bf16x8, *(const uint4*)(w1p + (long)ni * 16384));
    __syncthreads();

    for (int kt = 0; kt < 16; ++kt) {
        if (kt < 15) LOADX(kt + 1);
        char* cA = (char*)sA[kt & 1];
#pragma unroll
        for (int ks = 0; ks < 2; ++ks) {
            const int k32 = kt * 2 + ks;
            if (k32 < 31) {
#pragma unroll
                for (int ni = 0; ni < 2; ++ni)
                    bvp[(k32 + 1) & 1][ni] = __builtin_bit_cast(bf16x8,
                        *(const uint4*)(w1p + (long)ni * 16384 + (k32 + 1) * 512));
            }
            bf16x8 av[4];
#pragma unroll
            for (int mi = 0; mi < 4; ++mi) {
                int row = mi * 16 + (l & 15);
                int ch  = ks * 4 + (l >> 4);
                av[mi] = __builtin_bit_cast(bf16x8,
                    *(const uint4*)(cA + row * 128 + ((ch ^ (row & 7)) << 4)));
            }
#pragma unroll
            for (int mi = 0; mi < 4; ++mi)
#pragma unroll
                for (int ni = 0; ni < 2; ++ni)
                    acc1[mi][ni] = __builtin_amdgcn_mfma_f32_16x16x32_bf16(
                        av[mi], bvp[k32 & 1][ni], acc1[mi][ni], 0, 0, 0);
        }
        if (kt < 15) WRITEX((kt & 1) ^ 1);
        __syncthreads();
    }

    // epilogue 1: bias + relu + bf16 -> swizzled sH
#pragma unroll
    for (int mi = 0; mi < 4; ++mi)
#pragma unroll
        for (int r = 0; r < 4; ++r) {
            int row = mi * 16 + (l >> 4) * 4 + r;
#pragma unroll
            for (int ni = 0; ni < 2; ++ni) {
                int col = w * 32 + ni * 16 + (l & 15);
                float v = acc1[mi][ni][r] + bvv[ni];
                v = v > 0.f ? v : 0.f;
                *(unsigned short*)(cH + row * 512 + (((col >> 3) ^ (row & 7)) << 4)
                                   + (col & 7) * 2) = f2bf(v);
            }
        }
    __syncthreads();

    // ---------------- phase 2 ----------------
    const unsigned short* w2p = W2f + (((long)lid * 64 + w * 8) * 8) * 512 + (long)l * 8;
    // frag (nc*4+ni, ks) at w2p + (nc*4+ni)*4096 + ks*512   (shorts)

    bf16x8 pv[2][4];
#pragma unroll
    for (int ni = 0; ni < 4; ++ni)
        pv[0][ni] = __builtin_bit_cast(bf16x8, *(const uint4*)(w2p + (long)ni * 4096));

    f32x4 acc[4][4];
    float b2v[4];
#pragma unroll
    for (int s = 0; s < 16; ++s) {
        const int nc = s >> 3, ks = s & 7, cur = s & 1;
        if (ks == 0) {
#pragma unroll
            for (int mi = 0; mi < 4; ++mi)
#pragma unroll
                for (int ni = 0; ni < 4; ++ni) acc[mi][ni] = z4;
#pragma unroll
            for (int ni = 0; ni < 4; ++ni)
                b2v[ni] = b2[lid * DOUT + w * 128 + nc * 64 + ni * 16 + (l & 15)];
        }
        if (s < 15) {
            const int ns = s + 1, nq = (ns >> 3) * 4, ks1 = ns & 7;
#pragma unroll
            for (int ni = 0; ni < 4; ++ni)
                pv[cur ^ 1][ni] = __builtin_bit_cast(bf16x8,
                    *(const uint4*)(w2p + (long)(nq + ni) * 4096 + ks1 * 512));
        }
        bf16x8 av2[4];
#pragma unroll
        for (int mi = 0; mi < 4; ++mi) {
            int row = mi * 16 + (l & 15);
            int ch  = ks * 4 + (l >> 4);
            av2[mi] = __builtin_bit_cast(bf16x8,
                *(const uint4*)(cH + row * 512 + ((ch ^ (row & 7)) << 4)));
        }
#pragma unroll
        for (int mi = 0; mi < 4; ++mi)
#pragma unroll
            for (int ni = 0; ni < 4; ++ni)
                acc[mi][ni] = __builtin_amdgcn_mfma_f32_16x16x32_bf16(
                    av2[mi], pv[cur][ni], acc[mi][ni], 0, 0, 0);
        if (ks == 7) {
#pragma unroll
            for (int mi = 0; mi < 4; ++mi)
#pragma unroll
                for (int r = 0; r < 4; ++r) {
                    int row = mi * 16 + (l >> 4) * 4 + r;
#pragma unroll
                    for (int ni = 0; ni < 4; ++ni) {
                        int col = w * 128 + nc * 64 + ni * 16 + (l & 15);
                        y[((long)(s0 + row) * BZ + b) * DOUT + col] =
                            acc[mi][ni][r] + b2v[ni];
                    }
                }
        }
    }
#undef LOADX
#undef WRITEX
}

extern "C" void kernel_launch(void* const* d_in, const int* in_sizes, int n_in,
                              void* d_out, int out_size, void* d_ws, size_t ws_size,
                              hipStream_t stream) {
    const float* x    = (const float*)d_in[0];
    const int*   lang = (const int*)d_in[1];
    const float* W1   = (const float*)d_in[2];
    const float* b1   = (const float*)d_in[3];
    const float* W2   = (const float*)d_in[4];
    const float* b2   = (const float*)d_in[5];
    float* y = (float*)d_out;

    // ws: W1f bf16 [16][16][32][64][8] (8 MiB) | W2f bf16 [16][64][8][64][8] (8 MiB)
    unsigned short* W1f = (unsigned short*)d_ws;
    unsigned short* W2f = (unsigned short*)((char*)d_ws + (size_t)NLANG * HID * DIN * 2);

    prep_frags<DIN, HID><<<2048, 256, 0, stream>>>(W1, W1f);
    prep_frags<HID, DOUT><<<2048, 256, 0, stream>>>(W2, W2f);

    fused_mlp<<<dim3(BZ, SEQ / 64), 512, 0, stream>>>(x, W1f, b1, W2f, b2, lang, y);
}